// Round 11
// baseline (203.635 us; speedup 1.0000x reference)
//
#include <hip/hip_runtime.h>
#include <hip/hip_bf16.h>
#include <stdint.h>

#define DEVI __device__ __forceinline__

using u16 = unsigned short;
typedef __attribute__((ext_vector_type(8))) _Float16 halfx8;
typedef __attribute__((ext_vector_type(8))) unsigned short u16x8;
typedef __attribute__((ext_vector_type(4))) float f32x4;

// Problem dims (fixed by the reference)
constexpr int BB = 4, TT = 2048, CC = 1024, KD = 1024, VD = 1024;
constexpr int QKVW = 3072;                 // fused projection width
constexpr int OUTW = CC + VD;              // 2048
constexpr float INV_SQRT_K = 0.03125f;     // 1/sqrt(1024)

DEVI u16 f2h(float f) {
  _Float16 h = (_Float16)f;
  return __builtin_bit_cast(u16, h);
}
DEVI float h2f(u16 u) {
  return (float)__builtin_bit_cast(_Float16, u);
}

// async global->LDS, 16 B per lane. LDS dest is wave-uniform base + lane*16.
DEVI void gload16(const u16* g, u16* l) {
  __builtin_amdgcn_global_load_lds(
      (const __attribute__((address_space(1))) void*)g,
      (__attribute__((address_space(3))) void*)l, 16, 0, 0);
}

// ---- cast x to f16 (for MFMA) and copy x into out[:, :C] (fp32) ----
__global__ void cast_x_copy(const float* __restrict__ x, u16* __restrict__ xh,
                            float* __restrict__ out) {
  size_t i = (size_t)blockIdx.x * blockDim.x + threadIdx.x;  // over B*T*C/4
  float4 v = reinterpret_cast<const float4*>(x)[i];
  ushort4 u;
  u.x = f2h(v.x); u.y = f2h(v.y); u.z = f2h(v.z); u.w = f2h(v.w);
  reinterpret_cast<ushort4*>(xh)[i] = u;
  size_t e = i * 4;
  size_t bt = e / CC;
  int c = (int)(e % CC);
  *reinterpret_cast<float4*>(&out[bt * OUTW + c]) = v;
}

// ---- W{q,k,v} [C,N] f32 -> Wt sections [N,C] f16, one launch (z selects W) ----
__global__ void transpose_cast_w3(const float* __restrict__ Wq,
                                  const float* __restrict__ Wk,
                                  const float* __restrict__ Wv,
                                  u16* __restrict__ Wt) {
  __shared__ float tile[32][33];
  const float* W = (blockIdx.z == 0) ? Wq : (blockIdx.z == 1) ? Wk : Wv;
  u16* dst = Wt + (size_t)blockIdx.z * 1024 * 1024;
  int n0 = blockIdx.x * 32, c0 = blockIdx.y * 32;
  int tx = threadIdx.x, ty = threadIdx.y;  // 32 x 8
  for (int i = ty; i < 32; i += 8)
    tile[i][tx] = W[(size_t)(c0 + i) * KD + n0 + tx];
  __syncthreads();
  for (int i = ty; i < 32; i += 8)
    dst[(size_t)(n0 + i) * CC + c0 + tx] = f2h(tile[tx][i]);
}

// ---- concat biases -> bc[3072] ----
__global__ void concat_bias(const float* __restrict__ bq, const float* __restrict__ bk,
                            const float* __restrict__ bv, float* __restrict__ bc) {
  int n = blockIdx.x * 256 + threadIdx.x;
  float v = (n < 1024) ? bq[n] : (n < 2048) ? bk[n - 1024] : bv[n - 2048];
  bc[n] = v;
}

// ---- V cols of QKV [B*T,3072] -> Vt [B,VD,T] f16, scaled by Di[b][s] ----
// (runs after stats_combine; folds the softmax denominator into V)
__global__ void transpose_v(const u16* __restrict__ QKV, const float* __restrict__ Di,
                            u16* __restrict__ Vt) {
  __shared__ u16 tile[32][33];
  int b = blockIdx.z;
  int n0 = blockIdx.x * 32, s0 = blockIdx.y * 32;
  const u16* src = QKV + (size_t)b * TT * QKVW + 2048;  // V columns
  u16* dst = Vt + (size_t)b * VD * TT;
  int tx = threadIdx.x, ty = threadIdx.y;
  for (int i = ty; i < 32; i += 8)
    tile[i][tx] = src[(size_t)(s0 + i) * QKVW + n0 + tx];
  float di = Di[b * TT + s0 + tx];  // column scale (s = s0+tx in dst row layout)
  __syncthreads();
  for (int i = ty; i < 32; i += 8)
    dst[(size_t)(n0 + i) * TT + s0 + tx] = f2h(h2f(tile[tx][i]) * di);
}

// ---- 256x128-tile 8-wave f16 MFMA GEMM, 2-buffer / 3 blocks-per-CU ----
// Out = alpha*(A @ Bm^T)(+bias). A:[M,Kd] (lda), Bm:[N,Kd] (ldb), row-major.
// R10 analysis: the 3-buf/2-blk config was LDS-BW-bound (88 KB/K-tile/block;
// 176 KB/CU/K-tile = ~1570 cyc = measured). Fix: 2 buffers -> 50 KB LDS ->
// 3 blocks/CU soaking the LDS port + covering the depth-1 vmcnt(0) drain
// (per-K-tile compute ~1000+ cyc > ~900 cyc HBM latency, so depth-1 is enough).
// Race-free: stage(kt+1) targets buf[(kt+1)&1] = buf[(kt-1)&1], whose ds_reads
// all completed before barrier(kt-1); stage is issued at iteration start (T3).
// vmcnt(0)+barrier at iteration end = next buffer fully landed for all waves.
// Swizzle (both-sides, rule 21): linear LDS dest; source col-chunk and read
// col-chunk XORed with (row>>1)&3 -> conflict-free b128 (verified R5-R10: 0).
// SWZ==1: row-strip XCD swizzle (uniform-cost grids only; gx%8==0).
// CMASK: S-mode epilogue — P = exp(alpha*acc) for t>=s else 0 (f16; no max
//   subtraction: |alpha*S|<=~4) + fused column-sum partials into Dp.
template <typename OutT, int SWZ, bool CSKIP, bool KLIM, bool BIAS, bool CMASK>
__global__ __launch_bounds__(512, 2) void gemm_bt(
    const u16* __restrict__ A, const u16* __restrict__ Bm, OutT* __restrict__ Out,
    const float* __restrict__ bias, float* __restrict__ Dp,
    int Kd, int lda, int ldb, int ldo,
    long long strA, long long strB, long long strO, float alpha) {
  constexpr int BM = 256, BN = 128, BK = 32;
  constexpr int WM = 4, WN = 2;                // wave grid; wave tile 64x64
  constexpr int WR = 64, WC = 64;
  constexpr int MR = 4, NR = 4;                // frags per wave
  constexpr int ASZ = BM * BK, BSZ = BN * BK;  // u16 per buffer
  __shared__ u16 sA[2 * ASZ];  // 32 KB
  __shared__ u16 sB[2 * BSZ];  // 16 KB -> 50 KB total incl. reds -> 3 blocks/CU
  __shared__ float reds[CMASK ? WM : 1][CMASK ? BN : 1];

  int bx = blockIdx.x, by = blockIdx.y;
  if constexpr (SWZ == 1) {
    const int gx = gridDim.x;
    const int nx = gx >> 3;  // bx strip per XCD (gx % 8 == 0 at call sites)
    int fid = bx + gx * by;
    int xcd = fid & 7, idx = fid >> 3;
    bx = xcd * nx + idx % nx;
    by = idx / nx;
  }
  const int r0 = bx * BM, c0 = by * BN;
  if (CSKIP && c0 > r0 + BM - 1) return;  // tile fully masked; never read downstream
  A   += (size_t)blockIdx.z * strA;
  Bm  += (size_t)blockIdx.z * strB;
  Out += (size_t)blockIdx.z * strO;

  const int tid = threadIdx.x;
  const int lane = tid & 63;
  const int w = tid >> 6;            // 0..7
  const int wm = w / WN, wn = w % WN;
  const int l15 = lane & 15, l4 = lane >> 4;
  const int cswz8 = 8 * (l4 ^ ((l15 >> 1) & 3));  // swizzled read col (u16)

  // staging map: thread t covers row t>>2 (0..127; +128 for A line1), chunk t&3.
  // LDS dest linear (byte t*16); global source chunk pre-swizzled (rule 21).
  const int srow = tid >> 2;
  const int sc8 = 8 * ((tid & 3) ^ ((tid >> 3) & 3));  // chunk ^ ((srow>>1)&3)
  const u16* gA  = A  + (size_t)(r0 + srow) * lda + sc8;
  const u16* gA2 = gA + (size_t)128 * lda;
  const u16* gB  = Bm + (size_t)(c0 + srow) * ldb + sc8;
  const int sdst = tid * 8;  // u16 offset; A line1 at +4096

  f32x4 acc[MR][NR] = {};

  int kmax = Kd;
  if (KLIM) { int km = r0 + BM; kmax = km < Kd ? km : Kd; }
  const int NT = kmax / BK;  // >= 8 at all call sites

  auto stage = [&](int buf, int kt) {
    const int k0 = kt * BK;
    u16* da = sA + buf * ASZ + sdst;
    gload16(gA + k0, da);
    gload16(gA2 + k0, da + 4096);
    u16* db = sB + buf * BSZ + sdst;
    gload16(gB + k0, db);
  };

  stage(0, 0);
  asm volatile("s_waitcnt vmcnt(0)" ::: "memory");  // K-tile 0 landed
  __builtin_amdgcn_s_barrier();

  for (int kt = 0; kt < NT; ++kt) {
    const int buf = kt & 1;
    if (kt + 1 < NT) stage(buf ^ 1, kt + 1);  // issue BEFORE reads/MFMA (T3)
    const u16* rA = sA + buf * ASZ;
    const u16* rB = sB + buf * BSZ;
    halfx8 af[MR], bfv[NR];
#pragma unroll
    for (int n = 0; n < NR; ++n)
      bfv[n] = *reinterpret_cast<const halfx8*>(&rB[(wn * WC + n * 16 + l15) * BK + cswz8]);
#pragma unroll
    for (int m = 0; m < MR; ++m)
      af[m] = *reinterpret_cast<const halfx8*>(&rA[(wm * WR + m * 16 + l15) * BK + cswz8]);
    __builtin_amdgcn_s_setprio(1);
#pragma unroll
    for (int m = 0; m < MR; ++m)
#pragma unroll
      for (int n = 0; n < NR; ++n)
        acc[m][n] = __builtin_amdgcn_mfma_f32_16x16x32_f16(af[m], bfv[n], acc[m][n], 0, 0, 0);
    __builtin_amdgcn_s_setprio(0);
    if (kt + 1 < NT) {
      asm volatile("s_waitcnt vmcnt(0)" ::: "memory");  // next buffer landed
      __builtin_amdgcn_s_barrier();
    }
  }

  // epilogue: C/D layout col = lane&15, row = (lane>>4)*4 + reg  [m89/m91 verified]
  if constexpr (CMASK) {
    // P = exp(alpha*S) masked to t>=s, f16; fused column-sum partials.
#pragma unroll
    for (int n = 0; n < NR; ++n) {
      const int gcol = c0 + wn * WC + n * 16 + l15;
      float sm = 0.f;
#pragma unroll
      for (int m = 0; m < MR; ++m) {
        const int growb = r0 + wm * WR + m * 16 + l4 * 4;
#pragma unroll
        for (int r = 0; r < 4; ++r) {
          float p = 0.f;
          if (growb + r >= gcol) p = __expf(acc[m][n][r] * alpha);
          reinterpret_cast<u16*>(Out)[(size_t)(growb + r) * ldo + gcol] = f2h(p);
          sm += p;
        }
      }
      sm += __shfl_xor(sm, 16);
      sm += __shfl_xor(sm, 32);  // sum over this wave's 64 rows
      if (l4 == 0) reds[wm][wn * WC + n * 16 + l15] = sm;
    }
    __syncthreads();
    if (tid < BN) {  // combine WM row-strips, write block partial sum
      float d2 = 0.f;
#pragma unroll
      for (int i = 0; i < WM; ++i) d2 += reds[i][tid];
      Dp[((size_t)(r0 >> 8) * BB + blockIdx.z) * TT + c0 + tid] = d2;
    }
  } else {
#pragma unroll
    for (int m = 0; m < MR; ++m) {
      const int growb = r0 + wm * WR + m * 16 + l4 * 4;
#pragma unroll
      for (int n = 0; n < NR; ++n) {
        const int gcol = c0 + wn * WC + n * 16 + l15;
        float bvv = 0.f;
        if (BIAS) bvv = bias[gcol];
#pragma unroll
        for (int r = 0; r < 4; ++r) {
          float val = acc[m][n][r] * alpha + bvv;
          size_t off = (size_t)(growb + r) * ldo + gcol;
          if constexpr (sizeof(OutT) == 2) {
            reinterpret_cast<u16*>(Out)[off] = f2h(val);
          } else {
            reinterpret_cast<float*>(Out)[off] = val;
          }
        }
      }
    }
  }
}

// ---- combine row-tile partial sums -> Di = 1/denominator ----
// Tiles rt < s>>8 were causally skipped (never written) -> start at rt0.
__global__ void stats_combine(const float* __restrict__ Dp, float* __restrict__ Di) {
  int b = blockIdx.y;
  int s = blockIdx.x * 256 + threadIdx.x;
  int rt0 = s >> 8;
  float d = 0.f;
  for (int rt = rt0; rt < TT / 256; ++rt)
    d += Dp[((size_t)rt * BB + b) * TT + s];
  Di[b * TT + s] = 1.f / d;  // column always contains the diagonal -> d > 0
}

extern "C" void kernel_launch(void* const* d_in, const int* in_sizes, int n_in,
                              void* d_out, int out_size, void* d_ws, size_t ws_size,
                              hipStream_t stream) {
  const float* x  = (const float*)d_in[0];
  const float* Wq = (const float*)d_in[1];
  const float* bq = (const float*)d_in[2];
  const float* Wk = (const float*)d_in[3];
  const float* bk = (const float*)d_in[4];
  const float* Wv = (const float*)d_in[5];
  const float* bv = (const float*)d_in[6];
  float* out = (float*)d_out;
  char* ws = (char*)d_ws;
  constexpr size_t MB = 1024ull * 1024ull;

  // Workspace layout (max 135 MB), sequential-reuse aliases:
  u16* xh   = (u16*)(ws);              // 16 MB  [B*T, C] f16   (dead after proj)
  u16* QKV  = (u16*)(ws + 16 * MB);    // 48 MB  [B*T, 3072] f16: Q|K|V columns
  u16* Wt   = (u16*)(ws + 64 * MB);    // 6 MB   [3072, C] f16  (dead after proj)
  float* bc = (float*)(ws + 70 * MB);  // 12 KB  concat bias
  u16* SP   = (u16*)(ws + 71 * MB);    // 32 MB  [B,T,T] f16: P = exp(alpha*S)
  u16* Vt = xh;                        // alias: [B,VD,T] f16
  float* Dp = (float*)(ws + 64 * MB);  // alias Wt (dead after proj): 256 KB [8,B,T]
  float* Di = (float*)(ws + 65 * MB);  // 32 KB [B,T]

  cast_x_copy<<<dim3((BB * TT * CC / 4) / 256), dim3(256), 0, stream>>>(x, xh, out);
  dim3 tb(32, 8);
  transpose_cast_w3<<<dim3(KD / 32, CC / 32, 3), tb, 0, stream>>>(Wq, Wk, Wv, Wt);
  concat_bias<<<dim3(QKVW / 256), 256, 0, stream>>>(bq, bk, bv, bc);

  // fused projection: QKV = xh @ Wt^T + bc, row-strip XCD swizzle (gx=32)
  gemm_bt<u16, 1, false, false, true, false><<<dim3(32, QKVW / 128, 1), 512, 0, stream>>>(
      xh, Wt, QKV, bc, nullptr, CC, CC, CC, QKVW, 0, 0, 0, 1.f);

  // P = exp((Q @ K^T)/sqrt(K)) masked, f16; causal tiles skipped; fused col sums
  gemm_bt<u16, 0, true, false, false, true><<<dim3(TT / 256, TT / 128, BB), 512, 0, stream>>>(
      QKV, QKV + 1024, SP, nullptr, Dp, KD, QKVW, QKVW, TT,
      (long long)TT * QKVW, (long long)TT * QKVW, (long long)TT * TT, INV_SQRT_K);

  stats_combine<<<dim3(TT / 256, BB), 256, 0, stream>>>(Dp, Di);

  // Vt = (V cols of QKV)^T scaled by Di (softmax denominator folded into V)
  transpose_v<<<dim3(VD / 32, TT / 32, BB), tb, 0, stream>>>(QKV, Di, Vt);

  // read = P @ (Di*V) (= P @ Vt^T), K truncated at r0+256 (exact: P==0 above diag)
  gemm_bt<float, 0, false, true, false, false><<<dim3(TT / 256, VD / 128, BB), 512, 0, stream>>>(
      SP, Vt, out + CC, nullptr, nullptr, TT, TT, TT, OUTW,
      (long long)TT * TT, (long long)VD * TT, (long long)TT * OUTW, 1.f);
}

// Round 12
// 185.420 us; speedup vs baseline: 1.0982x; 1.0982x over previous
//
#include <hip/hip_runtime.h>
#include <hip/hip_bf16.h>
#include <stdint.h>

#define DEVI __device__ __forceinline__

using u16 = unsigned short;
typedef __attribute__((ext_vector_type(8))) _Float16 halfx8;
typedef __attribute__((ext_vector_type(8))) unsigned short u16x8;
typedef __attribute__((ext_vector_type(4))) float f32x4;

// Problem dims (fixed by the reference)
constexpr int BB = 4, TT = 2048, CC = 1024, KD = 1024, VD = 1024;
constexpr int QKVW = 3072;                 // fused projection width
constexpr int OUTW = CC + VD;              // 2048
constexpr float INV_SQRT_K = 0.03125f;     // 1/sqrt(1024)

DEVI u16 f2h(float f) {
  _Float16 h = (_Float16)f;
  return __builtin_bit_cast(u16, h);
}
DEVI float h2f(u16 u) {
  return (float)__builtin_bit_cast(_Float16, u);
}

// async global->LDS, 16 B per lane. LDS dest is wave-uniform base + lane*16.
DEVI void gload16(const u16* g, u16* l) {
  __builtin_amdgcn_global_load_lds(
      (const __attribute__((address_space(1))) void*)g,
      (__attribute__((address_space(3))) void*)l, 16, 0, 0);
}

// ---- cast x to f16 (for MFMA) and copy x into out[:, :C] (fp32) ----
__global__ void cast_x_copy(const float* __restrict__ x, u16* __restrict__ xh,
                            float* __restrict__ out) {
  size_t i = (size_t)blockIdx.x * blockDim.x + threadIdx.x;  // over B*T*C/4
  float4 v = reinterpret_cast<const float4*>(x)[i];
  ushort4 u;
  u.x = f2h(v.x); u.y = f2h(v.y); u.z = f2h(v.z); u.w = f2h(v.w);
  reinterpret_cast<ushort4*>(xh)[i] = u;
  size_t e = i * 4;
  size_t bt = e / CC;
  int c = (int)(e % CC);
  *reinterpret_cast<float4*>(&out[bt * OUTW + c]) = v;
}

// ---- W{q,k,v} [C,N] f32 -> Wt sections [N,C] f16, one launch (z selects W) ----
__global__ void transpose_cast_w3(const float* __restrict__ Wq,
                                  const float* __restrict__ Wk,
                                  const float* __restrict__ Wv,
                                  u16* __restrict__ Wt) {
  __shared__ float tile[32][33];
  const float* W = (blockIdx.z == 0) ? Wq : (blockIdx.z == 1) ? Wk : Wv;
  u16* dst = Wt + (size_t)blockIdx.z * 1024 * 1024;
  int n0 = blockIdx.x * 32, c0 = blockIdx.y * 32;
  int tx = threadIdx.x, ty = threadIdx.y;  // 32 x 8
  for (int i = ty; i < 32; i += 8)
    tile[i][tx] = W[(size_t)(c0 + i) * KD + n0 + tx];
  __syncthreads();
  for (int i = ty; i < 32; i += 8)
    dst[(size_t)(n0 + i) * CC + c0 + tx] = f2h(tile[tx][i]);
}

// ---- concat biases -> bc[3072] ----
__global__ void concat_bias(const float* __restrict__ bq, const float* __restrict__ bk,
                            const float* __restrict__ bv, float* __restrict__ bc) {
  int n = blockIdx.x * 256 + threadIdx.x;
  float v = (n < 1024) ? bq[n] : (n < 2048) ? bk[n - 1024] : bv[n - 2048];
  bc[n] = v;
}

// ---- V cols of QKV [B*T,3072] -> Vt [B,VD,T] f16, scaled by Di[b][s] ----
// (runs after stats_combine; folds the softmax denominator into V)
__global__ void transpose_v(const u16* __restrict__ QKV, const float* __restrict__ Di,
                            u16* __restrict__ Vt) {
  __shared__ u16 tile[32][33];
  int b = blockIdx.z;
  int n0 = blockIdx.x * 32, s0 = blockIdx.y * 32;
  const u16* src = QKV + (size_t)b * TT * QKVW + 2048;  // V columns
  u16* dst = Vt + (size_t)b * VD * TT;
  int tx = threadIdx.x, ty = threadIdx.y;
  for (int i = ty; i < 32; i += 8)
    tile[i][tx] = src[(size_t)(s0 + i) * QKVW + n0 + tx];
  float di = Di[b * TT + s0 + tx];  // column scale (s = s0+tx in dst row layout)
  __syncthreads();
  for (int i = ty; i < 32; i += 8)
    dst[(size_t)(n0 + i) * TT + s0 + tx] = f2h(h2f(tile[tx][i]) * di);
}

// ---- 256x128-tile 8-wave f16 MFMA GEMM — R10-proven loop (3 buf, depth-2) ----
// Out = alpha*(A @ Bm^T)(+bias). A:[M,Kd] (lda), Bm:[N,Kd] (ldb), row-major.
// 3 LDS buffers, BK=32, 2-deep counted-vmcnt pipeline. 74 KB -> 2 blocks/CU.
// (R11 depth-1/2-buf experiment REGRESSED 62->72.6us: vmcnt(0) drain per K-tile
//  with no occupancy gain. This exact config measured 62us/GEMM, ~830 TF proj.)
// Race-free: stage(kt+2) targets buf (kt+2)%3 = (kt-1)%3, whose ds_reads all
// completed before barrier(kt-1). vmcnt(3) at kt's end = kt+1's 3 loads landed,
// kt+2's in flight (never drains to 0 in steady state).
// Swizzle (both-sides, rule 21): linear LDS dest; source col-chunk and read
// col-chunk XORed with (row>>1)&3 -> conflict-free b128 (verified R5-R11: 0).
// SWZ==1: row-strip XCD swizzle (uniform-cost grids only; gx%8==0).
// CMASK: S-mode epilogue — P = exp(alpha*acc) for t>=s else 0 (f16; no max
//   subtraction: |alpha*S|<=~4) + fused column-sum partials into Dp.
template <typename OutT, int SWZ, bool CSKIP, bool KLIM, bool BIAS, bool CMASK>
__global__ __launch_bounds__(512, 2) void gemm_bt(
    const u16* __restrict__ A, const u16* __restrict__ Bm, OutT* __restrict__ Out,
    const float* __restrict__ bias, float* __restrict__ Dp,
    int Kd, int lda, int ldb, int ldo,
    long long strA, long long strB, long long strO, float alpha) {
  constexpr int BM = 256, BN = 128, BK = 32;
  constexpr int WM = 4, WN = 2;                // wave grid; wave tile 64x64
  constexpr int WR = 64, WC = 64;
  constexpr int MR = 4, NR = 4;                // frags per wave
  constexpr int ASZ = BM * BK, BSZ = BN * BK;  // u16 per buffer
  __shared__ u16 sA[3 * ASZ];  // 48 KB
  __shared__ u16 sB[3 * BSZ];  // 24 KB -> 74 KB total incl. reds -> 2 blocks/CU
  __shared__ float reds[CMASK ? WM : 1][CMASK ? BN : 1];

  int bx = blockIdx.x, by = blockIdx.y;
  if constexpr (SWZ == 1) {
    const int gx = gridDim.x;
    const int nx = gx >> 3;  // bx strip per XCD (gx % 8 == 0 at call sites)
    int fid = bx + gx * by;
    int xcd = fid & 7, idx = fid >> 3;
    bx = xcd * nx + idx % nx;
    by = idx / nx;
  }
  const int r0 = bx * BM, c0 = by * BN;
  if (CSKIP && c0 > r0 + BM - 1) return;  // tile fully masked; never read downstream
  A   += (size_t)blockIdx.z * strA;
  Bm  += (size_t)blockIdx.z * strB;
  Out += (size_t)blockIdx.z * strO;

  const int tid = threadIdx.x;
  const int lane = tid & 63;
  const int w = tid >> 6;            // 0..7
  const int wm = w / WN, wn = w % WN;
  const int l15 = lane & 15, l4 = lane >> 4;
  const int cswz8 = 8 * (l4 ^ ((l15 >> 1) & 3));  // swizzled read col (u16)

  // staging map: thread t covers row t>>2 (0..127; +128 for A line1), chunk t&3.
  // LDS dest linear (byte t*16); global source chunk pre-swizzled (rule 21).
  const int srow = tid >> 2;
  const int sc8 = 8 * ((tid & 3) ^ ((tid >> 3) & 3));  // chunk ^ ((srow>>1)&3)
  const u16* gA  = A  + (size_t)(r0 + srow) * lda + sc8;
  const u16* gA2 = gA + (size_t)128 * lda;
  const u16* gB  = Bm + (size_t)(c0 + srow) * ldb + sc8;
  const int sdst = tid * 8;  // u16 offset; A line1 at +4096

  f32x4 acc[MR][NR] = {};

  int kmax = Kd;
  if (KLIM) { int km = r0 + BM; kmax = km < Kd ? km : Kd; }
  const int NT = kmax / BK;  // >= 8 at all call sites

  auto stage = [&](int buf, int kt) {
    const int k0 = kt * BK;
    u16* da = sA + buf * ASZ + sdst;
    gload16(gA + k0, da);
    gload16(gA2 + k0, da + 4096);
    u16* db = sB + buf * BSZ + sdst;
    gload16(gB + k0, db);
  };

  stage(0, 0);
  stage(1, 1);
  asm volatile("s_waitcnt vmcnt(3)" ::: "memory");  // K-tile 0 landed (in-order)
  __builtin_amdgcn_s_barrier();

  int buf = 0;
  for (int kt = 0; kt < NT; ++kt) {
    int nb = buf + 2; if (nb >= 3) nb -= 3;  // (kt+2)%3
    const u16* rA = sA + buf * ASZ;
    const u16* rB = sB + buf * BSZ;
    halfx8 af[MR], bfv[NR];
#pragma unroll
    for (int n = 0; n < NR; ++n)
      bfv[n] = *reinterpret_cast<const halfx8*>(&rB[(wn * WC + n * 16 + l15) * BK + cswz8]);
#pragma unroll
    for (int m = 0; m < MR; ++m)
      af[m] = *reinterpret_cast<const halfx8*>(&rA[(wm * WR + m * 16 + l15) * BK + cswz8]);
    if (kt + 2 < NT) stage(nb, kt + 2);
    __builtin_amdgcn_s_setprio(1);
#pragma unroll
    for (int m = 0; m < MR; ++m)
#pragma unroll
      for (int n = 0; n < NR; ++n)
        acc[m][n] = __builtin_amdgcn_mfma_f32_16x16x32_f16(af[m], bfv[n], acc[m][n], 0, 0, 0);
    __builtin_amdgcn_s_setprio(0);
    if (kt + 2 < NT)      asm volatile("s_waitcnt vmcnt(3)" ::: "memory");  // kt+1 landed
    else if (kt + 1 < NT) asm volatile("s_waitcnt vmcnt(0)" ::: "memory");  // drain tail
    if (kt + 1 < NT) __builtin_amdgcn_s_barrier();
    buf = buf + 1; if (buf == 3) buf = 0;
  }

  // epilogue: C/D layout col = lane&15, row = (lane>>4)*4 + reg  [m89/m91 verified]
  if constexpr (CMASK) {
    // P = exp(alpha*S) masked to t>=s, f16; fused column-sum partials.
#pragma unroll
    for (int n = 0; n < NR; ++n) {
      const int gcol = c0 + wn * WC + n * 16 + l15;
      float sm = 0.f;
#pragma unroll
      for (int m = 0; m < MR; ++m) {
        const int growb = r0 + wm * WR + m * 16 + l4 * 4;
#pragma unroll
        for (int r = 0; r < 4; ++r) {
          float p = 0.f;
          if (growb + r >= gcol) p = __expf(acc[m][n][r] * alpha);
          reinterpret_cast<u16*>(Out)[(size_t)(growb + r) * ldo + gcol] = f2h(p);
          sm += p;
        }
      }
      sm += __shfl_xor(sm, 16);
      sm += __shfl_xor(sm, 32);  // sum over this wave's 64 rows
      if (l4 == 0) reds[wm][wn * WC + n * 16 + l15] = sm;
    }
    __syncthreads();
    if (tid < BN) {  // combine WM row-strips, write block partial sum
      float d2 = 0.f;
#pragma unroll
      for (int i = 0; i < WM; ++i) d2 += reds[i][tid];
      Dp[((size_t)(r0 >> 8) * BB + blockIdx.z) * TT + c0 + tid] = d2;
    }
  } else {
#pragma unroll
    for (int m = 0; m < MR; ++m) {
      const int growb = r0 + wm * WR + m * 16 + l4 * 4;
#pragma unroll
      for (int n = 0; n < NR; ++n) {
        const int gcol = c0 + wn * WC + n * 16 + l15;
        float bvv = 0.f;
        if (BIAS) bvv = bias[gcol];
#pragma unroll
        for (int r = 0; r < 4; ++r) {
          float val = acc[m][n][r] * alpha + bvv;
          size_t off = (size_t)(growb + r) * ldo + gcol;
          if constexpr (sizeof(OutT) == 2) {
            reinterpret_cast<u16*>(Out)[off] = f2h(val);
          } else {
            reinterpret_cast<float*>(Out)[off] = val;
          }
        }
      }
    }
  }
}

// ---- combine row-tile partial sums -> Di = 1/denominator ----
// Tiles rt < s>>8 were causally skipped (never written) -> start at rt0.
__global__ void stats_combine(const float* __restrict__ Dp, float* __restrict__ Di) {
  int b = blockIdx.y;
  int s = blockIdx.x * 256 + threadIdx.x;
  int rt0 = s >> 8;
  float d = 0.f;
  for (int rt = rt0; rt < TT / 256; ++rt)
    d += Dp[((size_t)rt * BB + b) * TT + s];
  Di[b * TT + s] = 1.f / d;  // column always contains the diagonal -> d > 0
}

extern "C" void kernel_launch(void* const* d_in, const int* in_sizes, int n_in,
                              void* d_out, int out_size, void* d_ws, size_t ws_size,
                              hipStream_t stream) {
  const float* x  = (const float*)d_in[0];
  const float* Wq = (const float*)d_in[1];
  const float* bq = (const float*)d_in[2];
  const float* Wk = (const float*)d_in[3];
  const float* bk = (const float*)d_in[4];
  const float* Wv = (const float*)d_in[5];
  const float* bv = (const float*)d_in[6];
  float* out = (float*)d_out;
  char* ws = (char*)d_ws;
  constexpr size_t MB = 1024ull * 1024ull;

  // Workspace layout (max 135 MB), sequential-reuse aliases:
  u16* xh   = (u16*)(ws);              // 16 MB  [B*T, C] f16   (dead after proj)
  u16* QKV  = (u16*)(ws + 16 * MB);    // 48 MB  [B*T, 3072] f16: Q|K|V columns
  u16* Wt   = (u16*)(ws + 64 * MB);    // 6 MB   [3072, C] f16  (dead after proj)
  float* bc = (float*)(ws + 70 * MB);  // 12 KB  concat bias
  u16* SP   = (u16*)(ws + 71 * MB);    // 32 MB  [B,T,T] f16: P = exp(alpha*S)
  u16* Vt = xh;                        // alias: [B,VD,T] f16
  float* Dp = (float*)(ws + 64 * MB);  // alias Wt (dead after proj): 256 KB [8,B,T]
  float* Di = (float*)(ws + 65 * MB);  // 32 KB [B,T]

  cast_x_copy<<<dim3((BB * TT * CC / 4) / 256), dim3(256), 0, stream>>>(x, xh, out);
  dim3 tb(32, 8);
  transpose_cast_w3<<<dim3(KD / 32, CC / 32, 3), tb, 0, stream>>>(Wq, Wk, Wv, Wt);
  concat_bias<<<dim3(QKVW / 256), 256, 0, stream>>>(bq, bk, bv, bc);

  // fused projection: QKV = xh @ Wt^T + bc, row-strip XCD swizzle (gx=32)
  gemm_bt<u16, 1, false, false, true, false><<<dim3(32, QKVW / 128, 1), 512, 0, stream>>>(
      xh, Wt, QKV, bc, nullptr, CC, CC, CC, QKVW, 0, 0, 0, 1.f);

  // P = exp((Q @ K^T)/sqrt(K)) masked, f16; causal tiles skipped; fused col sums
  gemm_bt<u16, 0, true, false, false, true><<<dim3(TT / 256, TT / 128, BB), 512, 0, stream>>>(
      QKV, QKV + 1024, SP, nullptr, Dp, KD, QKVW, QKVW, TT,
      (long long)TT * QKVW, (long long)TT * QKVW, (long long)TT * TT, INV_SQRT_K);

  stats_combine<<<dim3(TT / 256, BB), 256, 0, stream>>>(Dp, Di);

  // Vt = (V cols of QKV)^T scaled by Di (softmax denominator folded into V)
  transpose_v<<<dim3(VD / 32, TT / 32, BB), tb, 0, stream>>>(QKV, Di, Vt);

  // read = P @ (Di*V) (= P @ Vt^T), K truncated at r0+256 (exact: P==0 above diag)
  gemm_bt<float, 0, false, true, false, false><<<dim3(TT / 256, VD / 128, BB), 512, 0, stream>>>(
      SP, Vt, out + CC, nullptr, nullptr, TT, TT, TT, OUTW,
      (long long)TT * TT, (long long)VD * TT, (long long)TT * OUTW, 1.f);
}